// Round 1
// baseline (219.388 us; speedup 1.0000x reference)
//
#include <hip/hip_runtime.h>

// Problem constants: org/enh [32,3,512,512] fp32.
#define NB 32
#define PH 128                      // 512/4
#define PW 128
#define NPOOL  (NB * PH * PW)       // 524288 pooled elements
#define NBLK   (NPOOL / 256)        // 2048 blocks, 1 output/thread
#define INV48  (1.0f / 48.0f)       // /3 channels /16 pool window

typedef float vf4 __attribute__((ext_vector_type(4)));

// Stage A (fused): pooled[b,y,x] = (1/48) * sum_{c,dy,dx} (org - enh).
// One pooled output per thread: 24 independent dwordx4 loads (12 org + 12 enh),
// all issued before the reduction -> 24 KB in flight per wave, no manual
// pipeline, no loop tail. 2048 blocks (2x the old kernel's residency).
// Channel sum folded in: partial buffer shrinks 6 MB -> 2 MB and stage B's
// stencil drops from 15 loads/thread to 5.
__global__ __launch_bounds__(256) void pool_fused_kernel(
    const vf4* __restrict__ o4, const vf4* __restrict__ e4,
    float* __restrict__ pooled, float* __restrict__ out)
{
    // Zero the accumulator target for stage B's atomics (stream-ordered).
    if (blockIdx.x == 0 && threadIdx.x == 0) out[0] = 0.f;

    int idx = blockIdx.x * 256 + threadIdx.x;
    int x = idx & (PW - 1);
    int y = (idx >> 7) & (PH - 1);
    int b = idx >> 14;

    // float4-row index for (b, c, iy=4y+dy): ((b*3 + c)*512 + 4y + dy)*128 + x.
    // Lane i -> x = consecutive -> each load is a 1 KB contiguous wave access.
    int rbase = ((b * 3) * 512 + (y << 2)) * 128 + x;

    vf4 ov[12], ev[12];
#pragma unroll
    for (int i = 0; i < 12; ++i) {
        int c = i >> 2, dy = i & 3;
        int a = rbase + (c * 512 + dy) * 128;
        ov[i] = __builtin_nontemporal_load(o4 + a);
        ev[i] = __builtin_nontemporal_load(e4 + a);
    }

    vf4 d = {0.f, 0.f, 0.f, 0.f};
#pragma unroll
    for (int i = 0; i < 12; ++i)
        d += ov[i] - ev[i];

    pooled[idx] = ((d.x + d.y) + (d.z + d.w)) * INV48;
}

// Stage B: shift-difference sum-of-squares on the 2 MB pooled plane
// (L2/L3-resident), block-reduce, one atomicAdd per block (device-scope,
// replaces the old 2048-partial buffer + third kernel).
__global__ __launch_bounds__(256) void spa_reduce_kernel(
    const float* __restrict__ pooled, float* __restrict__ out)
{
    int idx = blockIdx.x * 256 + threadIdx.x;
    int x = idx & (PW - 1);
    int y = (idx >> 7) & (PH - 1);
    const float* p = pooled + (idx >> 14) * (PH * PW);

    float c  = p[y * PW + x];
    float l  = (x > 0)      ? p[y * PW + x - 1] : 0.f;
    float r  = (x < PW - 1) ? p[y * PW + x + 1] : 0.f;
    float u  = (y > 0)      ? p[(y - 1) * PW + x] : 0.f;
    float dn = (y < PH - 1) ? p[(y + 1) * PW + x] : 0.f;

    float dl = c - l, dr = c - r, du = c - u, dd = c - dn;
    float s = (dl * dl + dr * dr) + (du * du + dd * dd);

#pragma unroll
    for (int off = 32; off > 0; off >>= 1)
        s += __shfl_down(s, off, 64);

    __shared__ float smem[4];
    int lane = threadIdx.x & 63;
    int wid  = threadIdx.x >> 6;
    if (lane == 0) smem[wid] = s;
    __syncthreads();
    if (threadIdx.x == 0)
        atomicAdd(out, ((smem[0] + smem[1]) + (smem[2] + smem[3]))
                           * (1.0f / (float)NPOOL));
}

extern "C" void kernel_launch(void* const* d_in, const int* in_sizes, int n_in,
                              void* d_out, int out_size, void* d_ws, size_t ws_size,
                              hipStream_t stream) {
    const vf4* o4 = (const vf4*)d_in[0];
    const vf4* e4 = (const vf4*)d_in[1];
    float* out    = (float*)d_out;
    float* pooled = (float*)d_ws;      // 2 MB: [32][128][128]

    pool_fused_kernel<<<NBLK, 256, 0, stream>>>(o4, e4, pooled, out);
    spa_reduce_kernel<<<NBLK, 256, 0, stream>>>(pooled, out);
}